// Round 3
// baseline (271.843 us; speedup 1.0000x reference)
//
#include <hip/hip_runtime.h>

#define QSCALE 0.08838834764831845f   // (2*64)^-0.5

typedef __bf16 bf16x8 __attribute__((ext_vector_type(8)));
typedef __bf16 bf16x4 __attribute__((ext_vector_type(4)));
typedef float  f32x4  __attribute__((ext_vector_type(4)));

__device__ inline bf16x8 load16(const __bf16* p) { return *reinterpret_cast<const bf16x8*>(p); }

__device__ inline void gld_lds16(const void* g, void* l) {
  __builtin_amdgcn_global_load_lds((const __attribute__((address_space(1))) void*)g,
                                   (__attribute__((address_space(3))) void*)l, 16, 0, 0);
}

// compiler-fenced raw barrier (no vmcnt drain, unlike __syncthreads)
__device__ inline void wg_barrier() {
  asm volatile("" ::: "memory");
  __builtin_amdgcn_s_barrier();
  asm volatile("" ::: "memory");
}

// ---------------- prep kernels ----------------

__global__ void prep_x(const float* __restrict__ rgb, const float* __restrict__ spec,
                       __bf16* __restrict__ Xc) {
  int c = blockIdx.x * 256 + threadIdx.x;       // 8192*192 chunks of 8
  int row = c / 192, seg = c % 192;
  const float* src = (seg < 96) ? (rgb + row * 768 + seg * 8)
                                : (spec + row * 768 + (seg - 96) * 8);
  bf16x8 v;
#pragma unroll
  for (int i = 0; i < 8; ++i) v[i] = (__bf16)src[i];
  *reinterpret_cast<bf16x8*>(Xc + (size_t)c * 8) = v;
}

__global__ void prep_w(const float* __restrict__ wr, const float* __restrict__ wsp,
                       __bf16* __restrict__ Wc) {
  int c = blockIdx.x * 256 + threadIdx.x;       // 2304*192
  int n = c / 192, seg = c % 192;
  bool isR = seg < 96;
  const float* src = isR ? (wr + n * 768 + seg * 8)
                         : (wsp + n * 768 + (seg - 96) * 8);
  float sc = (n < 768) ? QSCALE : (n < 1536) ? 1.0f : (isR ? 1.0f : 0.5f);
  bf16x8 v;
#pragma unroll
  for (int i = 0; i < 8; ++i) v[i] = (__bf16)(src[i] * sc);
  *reinterpret_cast<bf16x8*>(Wc + (size_t)c * 8) = v;
}

__global__ void prep_bias(const float* __restrict__ rb, const float* __restrict__ sb,
                          float* __restrict__ bc) {
  int n = blockIdx.x * 256 + threadIdx.x;       // 2304 exactly
  float sr = (n < 768) ? QSCALE : 1.0f;
  float ss = (n < 768) ? QSCALE : (n < 1536) ? 1.0f : 0.5f;
  bc[n] = sr * rb[n] + ss * sb[n];
}

__global__ void prep_pw(const float* __restrict__ pw, __bf16* __restrict__ Pb) {
  int c = blockIdx.x * 256 + threadIdx.x;       // 768*96
  bf16x8 v;
#pragma unroll
  for (int i = 0; i < 8; ++i) v[i] = (__bf16)pw[(size_t)c * 8 + i];
  *reinterpret_cast<bf16x8*>(Pb + (size_t)c * 8) = v;
}

// ---------------- 256x256 deep-phase GEMM (QKV): C = A[M][K] @ B[N][K]^T ----------------
// 8 waves (2M x 4N), BK=64, 128 KiB LDS double-buffer, XOR-swizzled tiles.
// LDS tile layout: elem(R, c) at R*64 + (c ^ ((R&7)<<3))  [16B-chunk-preserving]
// Stage: linear LDS dest (global_load_lds), pre-swizzled global source column.
// Schedule per K-group (4 phases x 16 MFMA): stage tile t+1 at phase 0 (buf^1
// provably idle since previous group's end barrier); boundary vmcnt(0) drains
// only ~4-phase-old loads. No __syncthreads anywhere in this kernel.
template <int K, int NT, int NTILES>
__global__ __launch_bounds__(512, 2) void gemm256(const __bf16* __restrict__ A,
                                                  const __bf16* __restrict__ Bm,
                                                  const float* __restrict__ bias,
                                                  __bf16* __restrict__ Qo, __bf16* __restrict__ Ko,
                                                  __bf16* __restrict__ Vo) {
  __shared__ __bf16 smem[65536];   // 131072 B = 2 buf x (A 16384 + B 16384) elems
  const int tid = threadIdx.x;
  const int wid = tid >> 6, lane = tid & 63, r = lane & 15, g = lane >> 4;
  const int wr = wid >> 2, wc = wid & 3;          // wave grid 2M x 4N

  // bijective XCD swizzle: nwg = 8 * (nwg/8) exactly (288 or 96)
  int bid = blockIdx.x;
  int id = (bid & 7) * ((NTILES * 32) / 8) + (bid >> 3);
  const int bx = id % NTILES, by = id / NTILES;
  const int m0 = by * 256, n0 = bx * 256;

  // stage source precompute (de-swizzled column)
  const int srow = tid >> 3;                                    // 0..63
  const int scol = ((tid & 7) * 8) ^ (((tid >> 3) & 7) << 3);   // 0..63
  const __bf16* aS = A + (size_t)(m0 + srow) * K + scol;
  const __bf16* bS = Bm + (size_t)(n0 + srow) * K + scol;

  // fragment read swizzled column offsets (elems)
  const int sw = (r & 7) << 3;
  const int cswz0 = (g * 8) ^ sw;
  const int cswz1 = (32 + g * 8) ^ sw;

  f32x4 acc[8][4] = {};

#define STAGE(tk, db)                                                        \
  {                                                                          \
    const __bf16* ap_ = aS + (tk) * 64;                                      \
    const __bf16* bp_ = bS + (tk) * 64;                                      \
    _Pragma("unroll")                                                        \
    for (int h = 0; h < 4; ++h) {                                            \
      gld_lds16(ap_ + (size_t)h * 64 * K, &smem[(db) * 32768 + h * 4096 + wid * 512]); \
      gld_lds16(bp_ + (size_t)h * 64 * K, &smem[(db) * 32768 + 16384 + h * 4096 + wid * 512]); \
    }                                                                        \
  }

  STAGE(0, 0);
  asm volatile("s_waitcnt vmcnt(0)" ::: "memory");
  wg_barrier();

  for (int t = 0; t < NT; ++t) {
    const int buf = t & 1;
    const int aB = buf * 32768, bB = aB + 16384;
    if (t + 1 < NT) STAGE(t + 1, buf ^ 1);
    // all B fragments for this K-tile (8 x ds_read_b128)
    bf16x8 bfr[4][2];
#pragma unroll
    for (int n = 0; n < 4; ++n) {
      bfr[n][0] = load16(&smem[bB + (wc * 64 + n * 16 + r) * 64 + cswz0]);
      bfr[n][1] = load16(&smem[bB + (wc * 64 + n * 16 + r) * 64 + cswz1]);
    }
#pragma unroll
    for (int p = 0; p < 4; ++p) {
      bf16x8 afr[2][2];
#pragma unroll
      for (int i2 = 0; i2 < 2; ++i2) {
        afr[i2][0] = load16(&smem[aB + (wr * 128 + (p * 2 + i2) * 16 + r) * 64 + cswz0]);
        afr[i2][1] = load16(&smem[aB + (wr * 128 + (p * 2 + i2) * 16 + r) * 64 + cswz1]);
      }
      wg_barrier();
      __builtin_amdgcn_s_setprio(1);
#pragma unroll
      for (int i2 = 0; i2 < 2; ++i2)
#pragma unroll
        for (int n = 0; n < 4; ++n) {
          acc[p * 2 + i2][n] = __builtin_amdgcn_mfma_f32_16x16x32_bf16(afr[i2][0], bfr[n][0], acc[p * 2 + i2][n], 0, 0, 0);
          acc[p * 2 + i2][n] = __builtin_amdgcn_mfma_f32_16x16x32_bf16(afr[i2][1], bfr[n][1], acc[p * 2 + i2][n], 0, 0, 0);
        }
      __builtin_amdgcn_s_setprio(0);
      if (p == 3) asm volatile("s_waitcnt vmcnt(0)" ::: "memory");
      wg_barrier();
    }
  }
#undef STAGE

  // epilogue: scatter to Q/K [bh][l][64] and V^T [bh][64][l]
  const int sec = n0 / 768;   // 256 | 768 -> no straddle
#pragma unroll
  for (int m = 0; m < 8; ++m)
#pragma unroll
    for (int n = 0; n < 4; ++n)
#pragma unroll
      for (int j = 0; j < 4; ++j) {
        int i = m0 + wr * 128 + m * 16 + g * 4 + j;
        int c = n0 + wc * 64 + n * 16 + r;
        float v = acc[m][n][j] + bias[c];
        int b = i >> 10, l = i & 1023;
        int idx = c - sec * 768, h = idx >> 6, d = idx & 63;
        int bh = b * 12 + h;
        if (sec == 0)      Qo[(bh << 16) + (l << 6) + d] = (__bf16)v;
        else if (sec == 1) Ko[(bh << 16) + (l << 6) + d] = (__bf16)v;
        else               Vo[(bh << 16) + (d << 10) + l] = (__bf16)v;
      }
}

// ---------------- 128x128 GEMM (proj): Out f32 [M][768] = A @ B^T + bias ----------------
__global__ __launch_bounds__(256) void gemm_bt(const __bf16* __restrict__ A,
                                               const __bf16* __restrict__ Bm,
                                               const float* __restrict__ bias,
                                               float* __restrict__ Out) {
  const int K = 768;
  __shared__ __bf16 As[128 * 32], Bs[128 * 32];
  const int tid = threadIdx.x;
  const int m0 = blockIdx.y * 128, n0 = blockIdx.x * 128;
  const int wid = tid >> 6, lane = tid & 63, r = lane & 15, g = lane >> 4;
  const int wr = wid >> 1, wc = wid & 1;
  f32x4 acc[4][4] = {};
  const __bf16* gA = A + (size_t)(m0 + (tid >> 2)) * K + (tid & 3) * 8;
  const __bf16* gB = Bm + (size_t)(n0 + (tid >> 2)) * K + (tid & 3) * 8;
  __bf16* lA = As + wid * 512;
  __bf16* lB = Bs + wid * 512;

  for (int kt = 0; kt < K; kt += 32) {
    gld_lds16(gA + kt, lA);
    gld_lds16(gA + 64 * K + kt, lA + 2048);
    gld_lds16(gB + kt, lB);
    gld_lds16(gB + 64 * K + kt, lB + 2048);
    __syncthreads();
    bf16x8 af[4], bf[4];
#pragma unroll
    for (int i = 0; i < 4; ++i) af[i] = load16(&As[(wr * 64 + i * 16 + r) * 32 + g * 8]);
#pragma unroll
    for (int i = 0; i < 4; ++i) bf[i] = load16(&Bs[(wc * 64 + i * 16 + r) * 32 + g * 8]);
#pragma unroll
    for (int mi = 0; mi < 4; ++mi)
#pragma unroll
      for (int ni = 0; ni < 4; ++ni)
        acc[mi][ni] = __builtin_amdgcn_mfma_f32_16x16x32_bf16(af[mi], bf[ni], acc[mi][ni], 0, 0, 0);
    __syncthreads();
  }

#pragma unroll
  for (int mi = 0; mi < 4; ++mi)
#pragma unroll
    for (int ni = 0; ni < 4; ++ni)
#pragma unroll
      for (int j = 0; j < 4; ++j) {
        int i = m0 + wr * 64 + mi * 16 + g * 4 + j;
        int n = n0 + wc * 64 + ni * 16 + r;
        Out[(size_t)i * 768 + n] = acc[mi][ni][j] + bias[n];
      }
}

// ---------------- flash attention (swapped QK^T, 32 q-rows/wave) ----------------
__global__ __launch_bounds__(256) void attn_fwd(const __bf16* __restrict__ Qg,
                                                const __bf16* __restrict__ Kg,
                                                const __bf16* __restrict__ Vg,
                                                __bf16* __restrict__ Xo) {
  __shared__ __bf16 Pl[4][32 * 72];
  const int bh = blockIdx.x, qb = blockIdx.y;
  const int tid = threadIdx.x, wid = tid >> 6, lane = tid & 63, r = lane & 15, g = lane >> 4;
  const int q0 = qb * 128 + wid * 32;
  const __bf16* Qh = Qg + (size_t)bh * 65536;
  const __bf16* Kh = Kg + (size_t)bh * 65536;
  const __bf16* Vh = Vg + (size_t)bh * 65536;
  __bf16* Pw = &Pl[wid][0];

  bf16x8 qf[2][2];
#pragma unroll
  for (int mi = 0; mi < 2; ++mi)
#pragma unroll
    for (int ks = 0; ks < 2; ++ks)
      qf[mi][ks] = load16(&Qh[(q0 + mi * 16 + r) * 64 + ks * 32 + g * 8]);

  f32x4 o[2][4] = {};
  float m[2] = {-1e30f, -1e30f}, l[2] = {0.f, 0.f};

  for (int kv0 = 0; kv0 < 1024; kv0 += 64) {
    f32x4 s[2][4] = {};
#pragma unroll
    for (int ks = 0; ks < 2; ++ks) {
      bf16x8 kf[4];
#pragma unroll
      for (int ni = 0; ni < 4; ++ni) kf[ni] = load16(&Kh[(kv0 + ni * 16 + r) * 64 + ks * 32 + g * 8]);
#pragma unroll
      for (int mi = 0; mi < 2; ++mi)
#pragma unroll
        for (int ni = 0; ni < 4; ++ni)
          s[mi][ni] = __builtin_amdgcn_mfma_f32_16x16x32_bf16(kf[ni], qf[mi][ks], s[mi][ni], 0, 0, 0);
    }
#pragma unroll
    for (int mi = 0; mi < 2; ++mi) {
      float pmax = -1e30f;
#pragma unroll
      for (int ni = 0; ni < 4; ++ni)
#pragma unroll
        for (int j = 0; j < 4; ++j) pmax = fmaxf(pmax, s[mi][ni][j]);
      pmax = fmaxf(pmax, __shfl_xor(pmax, 16, 64));
      pmax = fmaxf(pmax, __shfl_xor(pmax, 32, 64));
      float mn = fmaxf(m[mi], pmax);
      float al = __expf(m[mi] - mn);
      m[mi] = mn;
      float rs = 0.f;
#pragma unroll
      for (int ni = 0; ni < 4; ++ni) {
        bf16x4 pk;
#pragma unroll
        for (int j = 0; j < 4; ++j) {
          float p = __expf(s[mi][ni][j] - mn);
          rs += p;
          pk[j] = (__bf16)p;
        }
        *reinterpret_cast<bf16x4*>(&Pw[(mi * 16 + r) * 72 + ni * 16 + g * 4]) = pk;
      }
      rs += __shfl_xor(rs, 16, 64);
      rs += __shfl_xor(rs, 32, 64);
      l[mi] = l[mi] * al + rs;
      if (__any(al < 1.0f)) {
        float ab[4];
#pragma unroll
        for (int j = 0; j < 4; ++j) ab[j] = __shfl(al, g * 4 + j, 64);
#pragma unroll
        for (int di = 0; di < 4; ++di)
#pragma unroll
          for (int j = 0; j < 4; ++j) o[mi][di][j] *= ab[j];
      }
    }
#pragma unroll
    for (int ks = 0; ks < 2; ++ks) {
      bf16x8 pa[2];
#pragma unroll
      for (int mi = 0; mi < 2; ++mi) pa[mi] = load16(&Pw[(mi * 16 + r) * 72 + ks * 32 + g * 8]);
#pragma unroll
      for (int di = 0; di < 4; ++di) {
        bf16x8 bv = load16(&Vh[(di * 16 + r) * 1024 + kv0 + ks * 32 + g * 8]);
#pragma unroll
        for (int mi = 0; mi < 2; ++mi)
          o[mi][di] = __builtin_amdgcn_mfma_f32_16x16x32_bf16(pa[mi], bv, o[mi][di], 0, 0, 0);
      }
    }
  }

  const int b = bh / 12, h = bh % 12;
#pragma unroll
  for (int mi = 0; mi < 2; ++mi) {
    float lb[4];
#pragma unroll
    for (int j = 0; j < 4; ++j) lb[j] = __shfl(l[mi], g * 4 + j, 64);
#pragma unroll
    for (int di = 0; di < 4; ++di)
#pragma unroll
      for (int j = 0; j < 4; ++j) {
        int q = q0 + mi * 16 + g * 4 + j;
        float v = o[mi][di][j] / lb[j];
        Xo[((size_t)b * 1024 + q) * 768 + h * 64 + di * 16 + r] = (__bf16)v;
      }
  }
}

// ---------------- launch ----------------

extern "C" void kernel_launch(void* const* d_in, const int* in_sizes, int n_in,
                              void* d_out, int out_size, void* d_ws, size_t ws_size,
                              hipStream_t stream) {
  const float* rgb   = (const float*)d_in[0];
  const float* spec  = (const float*)d_in[1];
  const float* rqkvw = (const float*)d_in[2];
  const float* rqkvb = (const float*)d_in[3];
  const float* sqkvw = (const float*)d_in[4];
  const float* sqkvb = (const float*)d_in[5];
  const float* projw = (const float*)d_in[6];
  const float* projb = (const float*)d_in[7];
  float* out = (float*)d_out;
  char* ws = (char*)d_ws;

  __bf16* Xc = (__bf16*)(ws);                    // 8192x1536 bf16   (25165824 B)
  __bf16* Wc = (__bf16*)(ws + 25165824);         // 2304x1536 bf16   ( 7077888 B)
  float*  bc = (float*) (ws + 32243712);         // 2304 f32         (    9216 B)
  __bf16* Pb = (__bf16*)(ws + 32252928);         // 768x768 bf16     ( 1179648 B)
  __bf16* Qb = (__bf16*)(ws + 33432576);         // 96x1024x64 bf16  (12582912 B)
  __bf16* Kb = (__bf16*)(ws + 46015488);         // 96x1024x64 bf16
  __bf16* Vb = (__bf16*)(ws + 58598400);         // V^T 96x64x1024 bf16
  __bf16* Xa = (__bf16*)(ws + 71181312);         // 8192x768 bf16    -> total 83764224 B

  prep_x   <<<6144, 256, 0, stream>>>(rgb, spec, Xc);
  prep_w   <<<1728, 256, 0, stream>>>(rqkvw, sqkvw, Wc);
  prep_bias<<<9,    256, 0, stream>>>(rqkvb, sqkvb, bc);
  prep_pw  <<<288,  256, 0, stream>>>(projw, Pb);

  gemm256<1536, 24, 9><<<288, 512, 0, stream>>>(Xc, Wc, bc, Qb, Kb, Vb);
  attn_fwd<<<dim3(96, 8), 256, 0, stream>>>(Qb, Kb, Vb, Xa);
  gemm_bt<<<dim3(6, 64), 256, 0, stream>>>(Xa, Pb, projb, out);
}

// Round 4
// 240.107 us; speedup vs baseline: 1.1322x; 1.1322x over previous
//
#include <hip/hip_runtime.h>

#define QSCALE 0.08838834764831845f   // (2*64)^-0.5

typedef __bf16 bf16x8 __attribute__((ext_vector_type(8)));
typedef __bf16 bf16x4 __attribute__((ext_vector_type(4)));
typedef float  f32x4  __attribute__((ext_vector_type(4)));

__device__ inline bf16x8 load16(const __bf16* p) { return *reinterpret_cast<const bf16x8*>(p); }

__device__ inline void gld_lds16(const void* g, void* l) {
  __builtin_amdgcn_global_load_lds((const __attribute__((address_space(1))) void*)g,
                                   (__attribute__((address_space(3))) void*)l, 16, 0, 0);
}

// compiler-fenced raw barrier (no vmcnt drain, unlike __syncthreads)
__device__ inline void wg_barrier() {
  asm volatile("" ::: "memory");
  __builtin_amdgcn_s_barrier();
  asm volatile("" ::: "memory");
}

// ---------------- prep kernels ----------------

__global__ void prep_x(const float* __restrict__ rgb, const float* __restrict__ spec,
                       __bf16* __restrict__ Xc) {
  int c = blockIdx.x * 256 + threadIdx.x;       // 8192*192 chunks of 8
  int row = c / 192, seg = c % 192;
  const float* src = (seg < 96) ? (rgb + row * 768 + seg * 8)
                                : (spec + row * 768 + (seg - 96) * 8);
  bf16x8 v;
#pragma unroll
  for (int i = 0; i < 8; ++i) v[i] = (__bf16)src[i];
  *reinterpret_cast<bf16x8*>(Xc + (size_t)c * 8) = v;
}

__global__ void prep_w(const float* __restrict__ wr, const float* __restrict__ wsp,
                       __bf16* __restrict__ Wc) {
  int c = blockIdx.x * 256 + threadIdx.x;       // 2304*192
  int n = c / 192, seg = c % 192;
  bool isR = seg < 96;
  const float* src = isR ? (wr + n * 768 + seg * 8)
                         : (wsp + n * 768 + (seg - 96) * 8);
  float sc = (n < 768) ? QSCALE : (n < 1536) ? 1.0f : (isR ? 1.0f : 0.5f);
  bf16x8 v;
#pragma unroll
  for (int i = 0; i < 8; ++i) v[i] = (__bf16)(src[i] * sc);
  *reinterpret_cast<bf16x8*>(Wc + (size_t)c * 8) = v;
}

__global__ void prep_bias(const float* __restrict__ rb, const float* __restrict__ sb,
                          float* __restrict__ bc) {
  int n = blockIdx.x * 256 + threadIdx.x;       // 2304 exactly
  float sr = (n < 768) ? QSCALE : 1.0f;
  float ss = (n < 768) ? QSCALE : (n < 1536) ? 1.0f : 0.5f;
  bc[n] = sr * rb[n] + ss * sb[n];
}

__global__ void prep_pw(const float* __restrict__ pw, __bf16* __restrict__ Pb) {
  int c = blockIdx.x * 256 + threadIdx.x;       // 768*96
  bf16x8 v;
#pragma unroll
  for (int i = 0; i < 8; ++i) v[i] = (__bf16)pw[(size_t)c * 8 + i];
  *reinterpret_cast<bf16x8*>(Pb + (size_t)c * 8) = v;
}

// ---------------- 128x128 dbuf GEMM: C = A[M][K] @ B[N][K]^T ----------------
// 4 waves (2m x 2n, 64x64 each), BK=64, 64 KiB LDS double-buffer -> 2 blocks/CU.
// XOR-swizzled LDS rows (elem (R,c) at R*64 + (c ^ ((R&7)<<3))): conflict-free
// (verified 0 conflicts in round 3). Stage via global_load_lds w=16, linear LDS
// dest + pre-swizzled global source column.
// Schedule/tile: STAGE(t+1)->buf^1; ds_read frags(buf); 32 MFMA; vmcnt(0);
// barrier. Safety: tile t-1's reads of buf^1 are consumed by its MFMAs before
// the t-1 end barrier, so STAGE(t+1) (issued after it) cannot race them.
// MODE 0: scatter to Q/K [bh][l][64] + V^T [bh][64][l] (+bias). MODE 1: f32 out.
template <int K, int NT, int NTX, int MODE>
__global__ __launch_bounds__(256, 2) void gemm128(const __bf16* __restrict__ A,
                                                  const __bf16* __restrict__ Bm,
                                                  const float* __restrict__ bias,
                                                  __bf16* __restrict__ Qo, __bf16* __restrict__ Ko,
                                                  __bf16* __restrict__ Vo, float* __restrict__ Out) {
  __shared__ __bf16 smem[32768];   // 65536 B = 2 buf x (A 8192 + B 8192) elems
  const int tid = threadIdx.x;
  const int wid = tid >> 6, lane = tid & 63, r = lane & 15, g = lane >> 4;
  const int wr = wid >> 1, wc = wid & 1;

  // bijective XCD swizzle (grid = NTX*64, divisible by 8)
  constexpr int PERX = (NTX * 64) / 8;
  int bid = blockIdx.x;
  int id = (bid & 7) * PERX + (bid >> 3);
  const int bx = id % NTX, by = id / NTX;
  const int m0 = by * 128, n0 = bx * 128;

  // stage source (de-swizzled column); dest elem = tid*8 per sweep
  const int t8 = tid >> 3;
  const int scol = ((tid & 7) * 8) ^ ((t8 & 7) << 3);
  const __bf16* aS = A + (size_t)(m0 + t8) * K + scol;
  const __bf16* bS = Bm + (size_t)(n0 + t8) * K + scol;

  // fragment-read swizzled column offsets
  const int sw = (r & 7) << 3;
  const int cs0 = (g * 8) ^ sw;
  const int cs1 = (32 + g * 8) ^ sw;

  f32x4 acc[4][4] = {};

#define STAGE(tk, db)                                                           \
  {                                                                             \
    _Pragma("unroll")                                                           \
    for (int s = 0; s < 4; ++s) {                                               \
      gld_lds16(aS + (size_t)(s * 32) * K + (tk) * 64,                          \
                &smem[(db) * 16384 + s * 2048 + wid * 512]);                    \
      gld_lds16(bS + (size_t)(s * 32) * K + (tk) * 64,                          \
                &smem[(db) * 16384 + 8192 + s * 2048 + wid * 512]);             \
    }                                                                           \
  }

  STAGE(0, 0);
  asm volatile("s_waitcnt vmcnt(0)" ::: "memory");
  wg_barrier();

  int buf = 0;
  for (int t = 0; t < NT; ++t) {
    const int aB = buf * 16384, bB = aB + 8192;
    if (t + 1 < NT) STAGE(t + 1, buf ^ 1);
    bf16x8 bfr[4][2], afr[4][2];
#pragma unroll
    for (int n = 0; n < 4; ++n) {
      bfr[n][0] = load16(&smem[bB + (wc * 64 + n * 16 + r) * 64 + cs0]);
      bfr[n][1] = load16(&smem[bB + (wc * 64 + n * 16 + r) * 64 + cs1]);
    }
#pragma unroll
    for (int m = 0; m < 4; ++m) {
      afr[m][0] = load16(&smem[aB + (wr * 64 + m * 16 + r) * 64 + cs0]);
      afr[m][1] = load16(&smem[aB + (wr * 64 + m * 16 + r) * 64 + cs1]);
    }
    __builtin_amdgcn_s_setprio(1);
#pragma unroll
    for (int m = 0; m < 4; ++m)
#pragma unroll
      for (int n = 0; n < 4; ++n) {
        acc[m][n] = __builtin_amdgcn_mfma_f32_16x16x32_bf16(afr[m][0], bfr[n][0], acc[m][n], 0, 0, 0);
        acc[m][n] = __builtin_amdgcn_mfma_f32_16x16x32_bf16(afr[m][1], bfr[n][1], acc[m][n], 0, 0, 0);
      }
    __builtin_amdgcn_s_setprio(0);
    asm volatile("s_waitcnt vmcnt(0)" ::: "memory");
    wg_barrier();
    buf ^= 1;
  }
#undef STAGE

  if (MODE == 0) {
    const int sec = n0 / 768;   // 128 | 768 -> no straddle
#pragma unroll
    for (int m = 0; m < 4; ++m)
#pragma unroll
      for (int n = 0; n < 4; ++n)
#pragma unroll
        for (int j = 0; j < 4; ++j) {
          int i = m0 + wr * 64 + m * 16 + g * 4 + j;
          int c = n0 + wc * 64 + n * 16 + r;
          float v = acc[m][n][j] + bias[c];
          int b = i >> 10, l = i & 1023;
          int idx = c - sec * 768, h = idx >> 6, d = idx & 63;
          int bh = b * 12 + h;
          if (sec == 0)      Qo[(bh << 16) + (l << 6) + d] = (__bf16)v;
          else if (sec == 1) Ko[(bh << 16) + (l << 6) + d] = (__bf16)v;
          else               Vo[(bh << 16) + (d << 10) + l] = (__bf16)v;
        }
  } else {
#pragma unroll
    for (int m = 0; m < 4; ++m)
#pragma unroll
      for (int n = 0; n < 4; ++n)
#pragma unroll
        for (int j = 0; j < 4; ++j) {
          int i = m0 + wr * 64 + m * 16 + g * 4 + j;
          int c = n0 + wc * 64 + n * 16 + r;
          Out[(size_t)i * 768 + c] = acc[m][n][j] + bias[c];
        }
  }
}

// ---------------- flash attention (swapped QK^T, 32 q-rows/wave) ----------------
__global__ __launch_bounds__(256) void attn_fwd(const __bf16* __restrict__ Qg,
                                                const __bf16* __restrict__ Kg,
                                                const __bf16* __restrict__ Vg,
                                                __bf16* __restrict__ Xo) {
  __shared__ __bf16 Pl[4][32 * 72];
  const int bh = blockIdx.x, qb = blockIdx.y;
  const int tid = threadIdx.x, wid = tid >> 6, lane = tid & 63, r = lane & 15, g = lane >> 4;
  const int q0 = qb * 128 + wid * 32;
  const __bf16* Qh = Qg + (size_t)bh * 65536;
  const __bf16* Kh = Kg + (size_t)bh * 65536;
  const __bf16* Vh = Vg + (size_t)bh * 65536;
  __bf16* Pw = &Pl[wid][0];

  bf16x8 qf[2][2];
#pragma unroll
  for (int mi = 0; mi < 2; ++mi)
#pragma unroll
    for (int ks = 0; ks < 2; ++ks)
      qf[mi][ks] = load16(&Qh[(q0 + mi * 16 + r) * 64 + ks * 32 + g * 8]);

  f32x4 o[2][4] = {};
  float m[2] = {-1e30f, -1e30f}, l[2] = {0.f, 0.f};

  for (int kv0 = 0; kv0 < 1024; kv0 += 64) {
    f32x4 s[2][4] = {};
#pragma unroll
    for (int ks = 0; ks < 2; ++ks) {
      bf16x8 kf[4];
#pragma unroll
      for (int ni = 0; ni < 4; ++ni) kf[ni] = load16(&Kh[(kv0 + ni * 16 + r) * 64 + ks * 32 + g * 8]);
#pragma unroll
      for (int mi = 0; mi < 2; ++mi)
#pragma unroll
        for (int ni = 0; ni < 4; ++ni)
          s[mi][ni] = __builtin_amdgcn_mfma_f32_16x16x32_bf16(kf[ni], qf[mi][ks], s[mi][ni], 0, 0, 0);
    }
#pragma unroll
    for (int mi = 0; mi < 2; ++mi) {
      float pmax = -1e30f;
#pragma unroll
      for (int ni = 0; ni < 4; ++ni)
#pragma unroll
        for (int j = 0; j < 4; ++j) pmax = fmaxf(pmax, s[mi][ni][j]);
      pmax = fmaxf(pmax, __shfl_xor(pmax, 16, 64));
      pmax = fmaxf(pmax, __shfl_xor(pmax, 32, 64));
      float mn = fmaxf(m[mi], pmax);
      float al = __expf(m[mi] - mn);
      m[mi] = mn;
      float rs = 0.f;
#pragma unroll
      for (int ni = 0; ni < 4; ++ni) {
        bf16x4 pk;
#pragma unroll
        for (int j = 0; j < 4; ++j) {
          float p = __expf(s[mi][ni][j] - mn);
          rs += p;
          pk[j] = (__bf16)p;
        }
        *reinterpret_cast<bf16x4*>(&Pw[(mi * 16 + r) * 72 + ni * 16 + g * 4]) = pk;
      }
      rs += __shfl_xor(rs, 16, 64);
      rs += __shfl_xor(rs, 32, 64);
      l[mi] = l[mi] * al + rs;
      if (__any(al < 1.0f)) {
        float ab[4];
#pragma unroll
        for (int j = 0; j < 4; ++j) ab[j] = __shfl(al, g * 4 + j, 64);
#pragma unroll
        for (int di = 0; di < 4; ++di)
#pragma unroll
          for (int j = 0; j < 4; ++j) o[mi][di][j] *= ab[j];
      }
    }
#pragma unroll
    for (int ks = 0; ks < 2; ++ks) {
      bf16x8 pa[2];
#pragma unroll
      for (int mi = 0; mi < 2; ++mi) pa[mi] = load16(&Pw[(mi * 16 + r) * 72 + ks * 32 + g * 8]);
#pragma unroll
      for (int di = 0; di < 4; ++di) {
        bf16x8 bv = load16(&Vh[(di * 16 + r) * 1024 + kv0 + ks * 32 + g * 8]);
#pragma unroll
        for (int mi = 0; mi < 2; ++mi)
          o[mi][di] = __builtin_amdgcn_mfma_f32_16x16x32_bf16(pa[mi], bv, o[mi][di], 0, 0, 0);
      }
    }
  }

  const int b = bh / 12, h = bh % 12;
#pragma unroll
  for (int mi = 0; mi < 2; ++mi) {
    float lb[4];
#pragma unroll
    for (int j = 0; j < 4; ++j) lb[j] = __shfl(l[mi], g * 4 + j, 64);
#pragma unroll
    for (int di = 0; di < 4; ++di)
#pragma unroll
      for (int j = 0; j < 4; ++j) {
        int q = q0 + mi * 16 + g * 4 + j;
        float v = o[mi][di][j] / lb[j];
        Xo[((size_t)b * 1024 + q) * 768 + h * 64 + di * 16 + r] = (__bf16)v;
      }
  }
}

// ---------------- launch ----------------

extern "C" void kernel_launch(void* const* d_in, const int* in_sizes, int n_in,
                              void* d_out, int out_size, void* d_ws, size_t ws_size,
                              hipStream_t stream) {
  const float* rgb   = (const float*)d_in[0];
  const float* spec  = (const float*)d_in[1];
  const float* rqkvw = (const float*)d_in[2];
  const float* rqkvb = (const float*)d_in[3];
  const float* sqkvw = (const float*)d_in[4];
  const float* sqkvb = (const float*)d_in[5];
  const float* projw = (const float*)d_in[6];
  const float* projb = (const float*)d_in[7];
  float* out = (float*)d_out;
  char* ws = (char*)d_ws;

  __bf16* Xc = (__bf16*)(ws);                    // 8192x1536 bf16   (25165824 B)
  __bf16* Wc = (__bf16*)(ws + 25165824);         // 2304x1536 bf16   ( 7077888 B)
  float*  bc = (float*) (ws + 32243712);         // 2304 f32         (    9216 B)
  __bf16* Pb = (__bf16*)(ws + 32252928);         // 768x768 bf16     ( 1179648 B)
  __bf16* Qb = (__bf16*)(ws + 33432576);         // 96x1024x64 bf16  (12582912 B)
  __bf16* Kb = (__bf16*)(ws + 46015488);         // 96x1024x64 bf16
  __bf16* Vb = (__bf16*)(ws + 58598400);         // V^T 96x64x1024 bf16
  __bf16* Xa = (__bf16*)(ws + 71181312);         // 8192x768 bf16    -> total 83764224 B

  prep_x   <<<6144, 256, 0, stream>>>(rgb, spec, Xc);
  prep_w   <<<1728, 256, 0, stream>>>(rqkvw, sqkvw, Wc);
  prep_bias<<<9,    256, 0, stream>>>(rqkvb, sqkvb, bc);
  prep_pw  <<<288,  256, 0, stream>>>(projw, Pb);

  gemm128<1536, 24, 18, 0><<<1152, 256, 0, stream>>>(Xc, Wc, bc, Qb, Kb, Vb, nullptr);
  attn_fwd<<<dim3(96, 8), 256, 0, stream>>>(Qb, Kb, Vb, Xa);
  gemm128<768, 12, 6, 1><<<384, 256, 0, stream>>>(Xa, Pb, projb, nullptr, nullptr, nullptr, out);
}

// Round 5
// 183.069 us; speedup vs baseline: 1.4849x; 1.3116x over previous
//
#include <hip/hip_runtime.h>

#define QSCALE 0.08838834764831845f   // (2*64)^-0.5

typedef __bf16 bf16x8 __attribute__((ext_vector_type(8)));
typedef __bf16 bf16x4 __attribute__((ext_vector_type(4)));
typedef float  f32x4  __attribute__((ext_vector_type(4)));

__device__ inline bf16x8 load16(const __bf16* p) { return *reinterpret_cast<const bf16x8*>(p); }

__device__ inline void gld_lds16(const void* g, void* l) {
  __builtin_amdgcn_global_load_lds((const __attribute__((address_space(1))) void*)g,
                                   (__attribute__((address_space(3))) void*)l, 16, 0, 0);
}

// compiler-fenced raw barrier (no vmcnt drain, unlike __syncthreads)
__device__ inline void wg_barrier() {
  asm volatile("" ::: "memory");
  __builtin_amdgcn_s_barrier();
  asm volatile("" ::: "memory");
}

// ---------------- prep kernels ----------------

__global__ void prep_x(const float* __restrict__ rgb, const float* __restrict__ spec,
                       __bf16* __restrict__ Xc) {
  int c = blockIdx.x * 256 + threadIdx.x;       // 8192*192 chunks of 8
  int row = c / 192, seg = c % 192;
  const float* src = (seg < 96) ? (rgb + row * 768 + seg * 8)
                                : (spec + row * 768 + (seg - 96) * 8);
  bf16x8 v;
#pragma unroll
  for (int i = 0; i < 8; ++i) v[i] = (__bf16)src[i];
  *reinterpret_cast<bf16x8*>(Xc + (size_t)c * 8) = v;
}

__global__ void prep_w(const float* __restrict__ wr, const float* __restrict__ wsp,
                       __bf16* __restrict__ Wc) {
  int c = blockIdx.x * 256 + threadIdx.x;       // 2304*192
  int n = c / 192, seg = c % 192;
  bool isR = seg < 96;
  const float* src = isR ? (wr + n * 768 + seg * 8)
                         : (wsp + n * 768 + (seg - 96) * 8);
  float sc = (n < 768) ? QSCALE : (n < 1536) ? 1.0f : (isR ? 1.0f : 0.5f);
  bf16x8 v;
#pragma unroll
  for (int i = 0; i < 8; ++i) v[i] = (__bf16)(src[i] * sc);
  *reinterpret_cast<bf16x8*>(Wc + (size_t)c * 8) = v;
}

__global__ void prep_bias(const float* __restrict__ rb, const float* __restrict__ sb,
                          float* __restrict__ bc) {
  int n = blockIdx.x * 256 + threadIdx.x;       // 2304 exactly
  float sr = (n < 768) ? QSCALE : 1.0f;
  float ss = (n < 768) ? QSCALE : (n < 1536) ? 1.0f : 0.5f;
  bc[n] = sr * rb[n] + ss * sb[n];
}

__global__ void prep_pw(const float* __restrict__ pw, __bf16* __restrict__ Pb) {
  int c = blockIdx.x * 256 + threadIdx.x;       // 768*96
  bf16x8 v;
#pragma unroll
  for (int i = 0; i < 8; ++i) v[i] = (__bf16)pw[(size_t)c * 8 + i];
  *reinterpret_cast<bf16x8*>(Pb + (size_t)c * 8) = v;
}

// ---------------- 128x128 dbuf GEMM: C = A[M][K] @ B[N][K]^T ----------------
// 4 waves (2m x 2n, 64x64 each), BK=64, 64 KiB LDS double-buffer -> 2 blocks/CU.
// XOR-swizzled LDS rows (elem (R,c) at R*64 + (c ^ ((R&7)<<3))): conflict-free
// (verified 0 conflicts, rounds 3/4). Stage via global_load_lds w=16, linear
// LDS dest + pre-swizzled global source column.
// MODE 0: scatter to Q/K [bh][l][64] + V^T [bh][64][l] (+bias). MODE 1: f32 out.
template <int K, int NT, int NTX, int MODE>
__global__ __launch_bounds__(256, 2) void gemm128(const __bf16* __restrict__ A,
                                                  const __bf16* __restrict__ Bm,
                                                  const float* __restrict__ bias,
                                                  __bf16* __restrict__ Qo, __bf16* __restrict__ Ko,
                                                  __bf16* __restrict__ Vo, float* __restrict__ Out) {
  __shared__ __bf16 smem[32768];   // 65536 B = 2 buf x (A 8192 + B 8192) elems
  const int tid = threadIdx.x;
  const int wid = tid >> 6, lane = tid & 63, r = lane & 15, g = lane >> 4;
  const int wr = wid >> 1, wc = wid & 1;

  // bijective XCD swizzle (grid = NTX*64, divisible by 8)
  constexpr int PERX = (NTX * 64) / 8;
  int bid = blockIdx.x;
  int id = (bid & 7) * PERX + (bid >> 3);
  const int bx = id % NTX, by = id / NTX;
  const int m0 = by * 128, n0 = bx * 128;

  // stage source (de-swizzled column); dest elem = tid*8 per sweep
  const int t8 = tid >> 3;
  const int scol = ((tid & 7) * 8) ^ ((t8 & 7) << 3);
  const __bf16* aS = A + (size_t)(m0 + t8) * K + scol;
  const __bf16* bS = Bm + (size_t)(n0 + t8) * K + scol;

  // fragment-read swizzled column offsets
  const int sw = (r & 7) << 3;
  const int cs0 = (g * 8) ^ sw;
  const int cs1 = (32 + g * 8) ^ sw;

  f32x4 acc[4][4] = {};

#define STAGE(tk, db)                                                           \
  {                                                                             \
    _Pragma("unroll")                                                           \
    for (int s = 0; s < 4; ++s) {                                               \
      gld_lds16(aS + (size_t)(s * 32) * K + (tk) * 64,                          \
                &smem[(db) * 16384 + s * 2048 + wid * 512]);                    \
      gld_lds16(bS + (size_t)(s * 32) * K + (tk) * 64,                          \
                &smem[(db) * 16384 + 8192 + s * 2048 + wid * 512]);             \
    }                                                                           \
  }

  STAGE(0, 0);
  asm volatile("s_waitcnt vmcnt(0)" ::: "memory");
  wg_barrier();

  int buf = 0;
  for (int t = 0; t < NT; ++t) {
    const int aB = buf * 16384, bB = aB + 8192;
    if (t + 1 < NT) STAGE(t + 1, buf ^ 1);
    bf16x8 bfr[4][2], afr[4][2];
#pragma unroll
    for (int n = 0; n < 4; ++n) {
      bfr[n][0] = load16(&smem[bB + (wc * 64 + n * 16 + r) * 64 + cs0]);
      bfr[n][1] = load16(&smem[bB + (wc * 64 + n * 16 + r) * 64 + cs1]);
    }
#pragma unroll
    for (int m = 0; m < 4; ++m) {
      afr[m][0] = load16(&smem[aB + (wr * 64 + m * 16 + r) * 64 + cs0]);
      afr[m][1] = load16(&smem[aB + (wr * 64 + m * 16 + r) * 64 + cs1]);
    }
    __builtin_amdgcn_s_setprio(1);
#pragma unroll
    for (int m = 0; m < 4; ++m)
#pragma unroll
      for (int n = 0; n < 4; ++n) {
        acc[m][n] = __builtin_amdgcn_mfma_f32_16x16x32_bf16(afr[m][0], bfr[n][0], acc[m][n], 0, 0, 0);
        acc[m][n] = __builtin_amdgcn_mfma_f32_16x16x32_bf16(afr[m][1], bfr[n][1], acc[m][n], 0, 0, 0);
      }
    __builtin_amdgcn_s_setprio(0);
    asm volatile("s_waitcnt vmcnt(0)" ::: "memory");
    wg_barrier();
    buf ^= 1;
  }
#undef STAGE

  if (MODE == 0) {
    const int sec = n0 / 768;   // 128 | 768 -> no straddle
#pragma unroll
    for (int m = 0; m < 4; ++m)
#pragma unroll
      for (int n = 0; n < 4; ++n)
#pragma unroll
        for (int j = 0; j < 4; ++j) {
          int i = m0 + wr * 64 + m * 16 + g * 4 + j;
          int c = n0 + wc * 64 + n * 16 + r;
          float v = acc[m][n][j] + bias[c];
          int b = i >> 10, l = i & 1023;
          int idx = c - sec * 768, h = idx >> 6, d = idx & 63;
          int bh = b * 12 + h;
          if (sec == 0)      Qo[(bh << 16) + (l << 6) + d] = (__bf16)v;
          else if (sec == 1) Ko[(bh << 16) + (l << 6) + d] = (__bf16)v;
          else               Vo[(bh << 16) + (d << 10) + l] = (__bf16)v;
        }
  } else {
#pragma unroll
    for (int m = 0; m < 4; ++m)
#pragma unroll
      for (int n = 0; n < 4; ++n)
#pragma unroll
        for (int j = 0; j < 4; ++j) {
          int i = m0 + wr * 64 + m * 16 + g * 4 + j;
          int c = n0 + wc * 64 + n * 16 + r;
          Out[(size_t)i * 768 + c] = acc[m][n][j] + bias[c];
        }
  }
}

// ---------------- flash attention (swapped QK^T + LDS-staged K/V) ----------------
// grid (96 heads, 8 qblocks) x 256 thr (4 waves, 32 q-rows each).
// K,V^T tiles [64][64] double-buffered in XOR-swizzled LDS, staged once per
// block via global_load_lds (was: per-wave redundant global frag loads).
// Schedule per kv-tile: STAGE(t+1)->buf^1; QK^T from buf; softmax; PV from
// buf; vmcnt(0)+barrier. Same race argument as gemm128.
__global__ __launch_bounds__(256, 3) void attn_fwd(const __bf16* __restrict__ Qg,
                                                   const __bf16* __restrict__ Kg,
                                                   const __bf16* __restrict__ Vg,
                                                   __bf16* __restrict__ Xo) {
  __shared__ __bf16 smem[25600];   // KV: 2buf x (K 4096 + V 4096) = 16384; P: 4x32x72 = 9216
  const int bh = blockIdx.x, qb = blockIdx.y;
  const int tid = threadIdx.x, wid = tid >> 6, lane = tid & 63, r = lane & 15, g = lane >> 4;
  const int q0 = qb * 128 + wid * 32;
  const __bf16* Qh = Qg + (size_t)bh * 65536;
  const __bf16* Kh = Kg + (size_t)bh * 65536;
  const __bf16* Vh = Vg + (size_t)bh * 65536;
  __bf16* Pw = &smem[16384 + wid * 2304];

  // staging lane geometry (identical swizzle family to gemm128; row&7 == lr)
  const int lr = lane >> 3;                       // 0..7
  const int swc = ((lane & 7) * 8) ^ (lr << 3);   // de-swizzled source column
  // fragment-read swizzled column offsets
  const int sw = (r & 7) << 3;
  const int cs0 = (g * 8) ^ sw;
  const int cs1 = (32 + g * 8) ^ sw;

  bf16x8 qf[2][2];
#pragma unroll
  for (int mi = 0; mi < 2; ++mi)
#pragma unroll
    for (int ks = 0; ks < 2; ++ks)
      qf[mi][ks] = load16(&Qh[(q0 + mi * 16 + r) * 64 + ks * 32 + g * 8]);

  f32x4 o[2][4] = {};
  float m[2] = {-1e30f, -1e30f}, l[2] = {0.f, 0.f};

  // K rows: kv0 + s*32 + wid*8 + lr (row stride 64); V rows: d = s*32 + wid*8 + lr (row stride 1024)
#define STAGE_KV(kv, db)                                                         \
  {                                                                              \
    _Pragma("unroll")                                                            \
    for (int s = 0; s < 2; ++s) {                                                \
      gld_lds16(Kh + (size_t)((kv) + s * 32 + wid * 8 + lr) * 64 + swc,          \
                &smem[(db) * 8192 + s * 2048 + wid * 512]);                      \
      gld_lds16(Vh + (size_t)(s * 32 + wid * 8 + lr) * 1024 + (kv) + swc,        \
                &smem[(db) * 8192 + 4096 + s * 2048 + wid * 512]);               \
    }                                                                            \
  }

  STAGE_KV(0, 0);
  asm volatile("s_waitcnt vmcnt(0)" ::: "memory");
  wg_barrier();

  int buf = 0;
  for (int t = 0; t < 16; ++t) {
    const int kB = buf * 8192, vB = kB + 4096;
    if (t + 1 < 16) STAGE_KV((t + 1) * 64, buf ^ 1);

    // S^T = K Q^T : lane holds s[mi][ni][j] = P[q=mi*16+r][kv=ni*16+g*4+j]
    f32x4 s[2][4] = {};
    bf16x8 kf[4][2];
#pragma unroll
    for (int ni = 0; ni < 4; ++ni) {
      kf[ni][0] = load16(&smem[kB + (ni * 16 + r) * 64 + cs0]);
      kf[ni][1] = load16(&smem[kB + (ni * 16 + r) * 64 + cs1]);
    }
    __builtin_amdgcn_s_setprio(1);
#pragma unroll
    for (int ks = 0; ks < 2; ++ks)
#pragma unroll
      for (int mi = 0; mi < 2; ++mi)
#pragma unroll
        for (int ni = 0; ni < 4; ++ni)
          s[mi][ni] = __builtin_amdgcn_mfma_f32_16x16x32_bf16(kf[ni][ks], qf[mi][ks], s[mi][ni], 0, 0, 0);
    __builtin_amdgcn_s_setprio(0);

    // online softmax: 16 in-lane values per q-row, cross-g reduce (xor 16, 32)
#pragma unroll
    for (int mi = 0; mi < 2; ++mi) {
      float pmax = -1e30f;
#pragma unroll
      for (int ni = 0; ni < 4; ++ni)
#pragma unroll
        for (int j = 0; j < 4; ++j) pmax = fmaxf(pmax, s[mi][ni][j]);
      pmax = fmaxf(pmax, __shfl_xor(pmax, 16, 64));
      pmax = fmaxf(pmax, __shfl_xor(pmax, 32, 64));
      float mn = fmaxf(m[mi], pmax);
      float al = __expf(m[mi] - mn);
      m[mi] = mn;
      float rs = 0.f;
#pragma unroll
      for (int ni = 0; ni < 4; ++ni) {
        bf16x4 pk;
#pragma unroll
        for (int j = 0; j < 4; ++j) {
          float p = __expf(s[mi][ni][j] - mn);
          rs += p;
          pk[j] = (__bf16)p;
        }
        *reinterpret_cast<bf16x4*>(&Pw[(mi * 16 + r) * 72 + ni * 16 + g * 4]) = pk;
      }
      rs += __shfl_xor(rs, 16, 64);
      rs += __shfl_xor(rs, 32, 64);
      l[mi] = l[mi] * al + rs;
      if (__any(al < 1.0f)) {
        float ab[4];
#pragma unroll
        for (int j = 0; j < 4; ++j) ab[j] = __shfl(al, g * 4 + j, 64);
#pragma unroll
        for (int di = 0; di < 4; ++di)
#pragma unroll
          for (int j = 0; j < 4; ++j) o[mi][di][j] *= ab[j];
      }
    }

    // O += P V  (A = P from per-wave LDS; B = V^T tile from swizzled LDS)
#pragma unroll
    for (int ks = 0; ks < 2; ++ks) {
      bf16x8 pa[2];
#pragma unroll
      for (int mi = 0; mi < 2; ++mi) pa[mi] = load16(&Pw[(mi * 16 + r) * 72 + ks * 32 + g * 8]);
#pragma unroll
      for (int di = 0; di < 4; ++di) {
        bf16x8 bv = load16(&smem[vB + (di * 16 + r) * 64 + (ks ? cs1 : cs0)]);
#pragma unroll
        for (int mi = 0; mi < 2; ++mi)
          o[mi][di] = __builtin_amdgcn_mfma_f32_16x16x32_bf16(pa[mi], bv, o[mi][di], 0, 0, 0);
      }
    }

    asm volatile("s_waitcnt vmcnt(0)" ::: "memory");
    wg_barrier();
    buf ^= 1;
  }
#undef STAGE_KV

  const int b = bh / 12, h = bh % 12;
#pragma unroll
  for (int mi = 0; mi < 2; ++mi) {
    float lb[4];
#pragma unroll
    for (int j = 0; j < 4; ++j) lb[j] = __shfl(l[mi], g * 4 + j, 64);
#pragma unroll
    for (int di = 0; di < 4; ++di)
#pragma unroll
      for (int j = 0; j < 4; ++j) {
        int q = q0 + mi * 16 + g * 4 + j;
        float v = o[mi][di][j] / lb[j];
        Xo[((size_t)b * 1024 + q) * 768 + h * 64 + di * 16 + r] = (__bf16)v;
      }
  }
}

// ---------------- launch ----------------

extern "C" void kernel_launch(void* const* d_in, const int* in_sizes, int n_in,
                              void* d_out, int out_size, void* d_ws, size_t ws_size,
                              hipStream_t stream) {
  const float* rgb   = (const float*)d_in[0];
  const float* spec  = (const float*)d_in[1];
  const float* rqkvw = (const float*)d_in[2];
  const float* rqkvb = (const float*)d_in[3];
  const float* sqkvw = (const float*)d_in[4];
  const float* sqkvb = (const float*)d_in[5];
  const float* projw = (const float*)d_in[6];
  const float* projb = (const float*)d_in[7];
  float* out = (float*)d_out;
  char* ws = (char*)d_ws;

  __bf16* Xc = (__bf16*)(ws);                    // 8192x1536 bf16   (25165824 B)
  __bf16* Wc = (__bf16*)(ws + 25165824);         // 2304x1536 bf16   ( 7077888 B)
  float*  bc = (float*) (ws + 32243712);         // 2304 f32         (    9216 B)
  __bf16* Pb = (__bf16*)(ws + 32252928);         // 768x768 bf16     ( 1179648 B)
  __bf16* Qb = (__bf16*)(ws + 33432576);         // 96x1024x64 bf16  (12582912 B)
  __bf16* Kb = (__bf16*)(ws + 46015488);         // 96x1024x64 bf16
  __bf16* Vb = (__bf16*)(ws + 58598400);         // V^T 96x64x1024 bf16
  __bf16* Xa = (__bf16*)(ws + 71181312);         // 8192x768 bf16    -> total 83764224 B

  prep_x   <<<6144, 256, 0, stream>>>(rgb, spec, Xc);
  prep_w   <<<1728, 256, 0, stream>>>(rqkvw, sqkvw, Wc);
  prep_bias<<<9,    256, 0, stream>>>(rqkvb, sqkvb, bc);
  prep_pw  <<<288,  256, 0, stream>>>(projw, Pb);

  gemm128<1536, 24, 18, 0><<<1152, 256, 0, stream>>>(Xc, Wc, bc, Qb, Kb, Vb, nullptr);
  attn_fwd<<<dim3(96, 8), 256, 0, stream>>>(Qb, Kb, Vb, Xa);
  gemm128<768, 12, 6, 1><<<384, 256, 0, stream>>>(Xa, Pb, projb, nullptr, nullptr, nullptr, out);
}